// Round 1
// baseline (968.094 us; speedup 1.0000x reference)
//
#include <hip/hip_runtime.h>

// CombinedBandPassFilter: 40-band FIR (K=769, 'same' padding) over x[32,1,32768]
// out[b,0,band,t] = sum_k x[b, t+k-384] * kernels[band, k]
//
// fp32 VALU direct conv, register-tiled:
//   - 1 block = (batch, band, 4096-wide tile), 256 threads x 16 outputs/thread
//   - x tile + halo staged in LDS with XOR swizzle (conflict-free ds_read_b128)
//   - filter taps read via wave-uniform global loads (s_load path, SMEM pipe)

#define T_LEN    32768
#define N_BANDS  40
#define BATCH    32
#define K_TAPS   769
#define PAD      384
#define TILE     4096
#define OPT      16
#define NTHREADS 256
#define N_TILES  (T_LEN / TILE)            // 8
#define XS_LEN   (TILE + K_TAPS - 1)       // 4864 floats = 19456 B

// XOR swizzle: rows are 16 floats (64 B). Swap the 16B-column bits [3:2] with
// row bits [6:5] so 8 consecutive rows cover all 8 16B slots of a 128B bank
// line -> ds_read_b128 at 64B lane stride is conflict-free.
__device__ __forceinline__ int swz(int i) {
    int r = i >> 4;
    int c = (i >> 2) & 3;
    c ^= (r >> 1) & 3;
    return (r << 4) | (c << 2) | (i & 3);
}

__global__ __launch_bounds__(NTHREADS, 4)
void conv_bands(const float* __restrict__ x, const float* __restrict__ kernels,
                float* __restrict__ out) {
    __shared__ float xs[XS_LEN];
    const int tid  = threadIdx.x;
    const int bx   = blockIdx.x;
    const int tile = bx & (N_TILES - 1);
    const int band = (bx >> 3) % N_BANDS;
    const int b    = bx / (N_TILES * N_BANDS);
    const int t0   = tile * TILE;

    // Stage x[t0-384 .. t0+4096+384) into LDS (zero-filled at sequence edges).
    const float* xb = x + (size_t)b * T_LEN;
    for (int i = tid; i < XS_LEN; i += NTHREADS) {
        int g = t0 - PAD + i;
        float v = (g >= 0 && g < T_LEN) ? xb[g] : 0.0f;
        xs[swz(i)] = v;
    }
    __syncthreads();

    const float* kh = kernels + band * K_TAPS;   // wave-uniform accesses
    float acc[OPT];
    #pragma unroll
    for (int j = 0; j < OPT; ++j) acc[j] = 0.0f;

    const float4* xs4 = (const float4*)xs;
    // Main loop: 48 x (load 32-float window as 8x ds_read_b128, 256 FMAs)
    for (int k0 = 0; k0 < 768; k0 += 16) {
        const int R = tid + (k0 >> 4);   // window row base
        float w[32];
        #pragma unroll
        for (int c = 0; c < 8; ++c) {
            int r  = R + (c >> 2);
            int f4 = (r << 2) | ((c & 3) ^ ((r >> 1) & 3));   // swizzled float4 idx
            float4 v = xs4[f4];
            w[c * 4 + 0] = v.x; w[c * 4 + 1] = v.y;
            w[c * 4 + 2] = v.z; w[c * 4 + 3] = v.w;
        }
        #pragma unroll
        for (int kk = 0; kk < 16; ++kk) {
            float hk = kh[k0 + kk];      // uniform -> s_load
            #pragma unroll
            for (int j = 0; j < OPT; ++j)
                acc[j] = fmaf(hk, w[kk + j], acc[j]);
        }
    }
    // Tail tap k = 768
    {
        float hk = kh[768];
        int base = (tid + 48) << 4;
        #pragma unroll
        for (int j = 0; j < OPT; ++j)
            acc[j] = fmaf(hk, xs[swz(base + j)], acc[j]);
    }

    // Coalesced 16-float (4x float4) store per thread.
    float* ob = out + (((size_t)b * N_BANDS + band) * T_LEN) + t0 + tid * OPT;
    #pragma unroll
    for (int c = 0; c < 4; ++c) {
        ((float4*)ob)[c] = make_float4(acc[4*c+0], acc[4*c+1],
                                       acc[4*c+2], acc[4*c+3]);
    }
}

extern "C" void kernel_launch(void* const* d_in, const int* in_sizes, int n_in,
                              void* d_out, int out_size, void* d_ws, size_t ws_size,
                              hipStream_t stream) {
    const float* x       = (const float*)d_in[0];
    const float* kernels = (const float*)d_in[1];
    float* out           = (float*)d_out;
    dim3 grid(N_TILES * N_BANDS * BATCH);   // 10240 blocks
    conv_bands<<<grid, NTHREADS, 0, stream>>>(x, kernels, out);
}

// Round 2
// 342.560 us; speedup vs baseline: 2.8261x; 2.8261x over previous
//
#include <hip/hip_runtime.h>

// CombinedBandPassFilter as MFMA GEMM:
//   out[b, band, t] = sum_k H[band, k] * x[b, t + k - 384]
// = A(48x800, zero-padded H) x B(800 x N) Toeplitz, N = 32*32768.
// bf16 3-term split for fp32-grade accuracy: xh*hh + xl*hh + xh*hl, fp32 acc.
//
// Per block: output tile 48 bands x BN=128 time, 25 K-steps of 32 taps.
//  - x window (928 fp32) staged once in LDS
//  - per K-step: im2col B tile [128][32] bf16 (hi+lo) built in LDS with a
//    16B-slot swizzle (slot = (g + (n>>1)) & 3) -> conflict-free b128 R/W
//  - filter fragments pre-packed to MFMA lane order in d_ws by prep kernel,
//    loaded directly global->VGPR (L2-hot, 153.6 KB total)

typedef __attribute__((ext_vector_type(8))) short short8;
typedef __attribute__((ext_vector_type(4))) float f32x4;

#define T_LEN   32768
#define BATCH   32
#define NBANDS  40
#define KTAPS   769
#define NSTEP   25            // 25*32 = 800 padded taps
#define PADL    384
#define BN      128
#define XRAW    928           // max used index 926

__device__ __forceinline__ ushort f2bf(float f) {          // RNE float->bf16
    unsigned u = __float_as_uint(f);
    return (ushort)((u + 0x7FFFu + ((u >> 16) & 1u)) >> 16);
}
__device__ __forceinline__ float bf2f(ushort h) {
    return __uint_as_float(((unsigned)h) << 16);
}

// Pack H into MFMA A-fragment order: Ah/Al[(c*3+mt)*64 + lane] = 8 bf16
// (band = mt*16 + (lane&15), k = c*32 + 8*(lane>>4) + j), zero-padded.
__global__ void prep_filters(const float* __restrict__ kern,
                             ushort* __restrict__ Ah, ushort* __restrict__ Al) {
    const int blk = blockIdx.x;            // 0..74 = c*3 + mt
    const int c = blk / 3, mt = blk - 3 * c;
    const int l = threadIdx.x;             // 0..63
    const int band = mt * 16 + (l & 15);
    const int kb = c * 32 + 8 * (l >> 4);
    union { ushort u[8]; uint4 v; } ah, al;
    #pragma unroll
    for (int j = 0; j < 8; ++j) {
        const int k = kb + j;
        const float h = (band < NBANDS && k < KTAPS) ? kern[band * KTAPS + k] : 0.f;
        const ushort hh = f2bf(h);
        ah.u[j] = hh;
        al.u[j] = f2bf(h - bf2f(hh));
    }
    ((uint4*)Ah)[blk * 64 + l] = ah.v;
    ((uint4*)Al)[blk * 64 + l] = al.v;
}

__global__ __launch_bounds__(256, 4)
void conv_mfma(const float* __restrict__ x,
               const ushort* __restrict__ Ah, const ushort* __restrict__ Al,
               float* __restrict__ out) {
    __shared__ float  xraw[XRAW];
    __shared__ ushort Bh[BN * 32];    // row n: taps in 4 swizzled 16B slots
    __shared__ ushort Bl[BN * 32];

    const int tid = threadIdx.x;
    const int bx  = blockIdx.x;
    const int b   = bx >> 8;                   // 256 tiles per batch
    const int t0  = (bx & 255) * BN;
    const float* xb = x + (size_t)b * T_LEN;

    for (int i = tid; i < XRAW; i += 256) {
        const int g = t0 - PADL + i;
        xraw[i] = (g >= 0 && g < T_LEN) ? xb[g] : 0.f;
    }
    __syncthreads();

    const int wave = tid >> 6, l = tid & 63;
    const int nl = l & 15, gl = l >> 4;

    f32x4 acc[2][3];
    #pragma unroll
    for (int q = 0; q < 2; ++q)
        #pragma unroll
        for (int mt = 0; mt < 3; ++mt)
            acc[q][mt] = (f32x4){0.f, 0.f, 0.f, 0.f};

    for (int c = 0; c < NSTEP; ++c) {
        // ---- stage im2col B tile (hi+lo) for taps [c*32, c*32+32) ----
        if (tid < 152) {                      // chunk s covers x[c*32+s .. +8)
            const int s = tid;
            union { ushort u[8]; uint4 v; } hi, lo;
            #pragma unroll
            for (int j = 0; j < 8; ++j) {
                const float v = xraw[c * 32 + s + j];
                const ushort h = f2bf(v);
                hi.u[j] = h;
                lo.u[j] = f2bf(v - bf2f(h));
            }
            #pragma unroll
            for (int g = 0; g < 4; ++g) {
                const int n = s - 8 * g;      // row n, slot covering k=8g..8g+7
                if ((unsigned)n < BN) {
                    const int slot = (g + (n >> 1)) & 3;
                    ((uint4*)Bh)[n * 4 + slot] = hi.v;
                    ((uint4*)Bl)[n * 4 + slot] = lo.v;
                }
            }
        }
        __syncthreads();

        // ---- A fragments straight from global (L2-hot, lane-packed) ----
        union { uint4 v; short8 s8; } afh[3], afl[3], bfh[2], bfl[2];
        const uint4* Ah4 = (const uint4*)Ah + (size_t)c * 192;
        const uint4* Al4 = (const uint4*)Al + (size_t)c * 192;
        #pragma unroll
        for (int mt = 0; mt < 3; ++mt) {
            afh[mt].v = Ah4[mt * 64 + l];
            afl[mt].v = Al4[mt * 64 + l];
        }
        // ---- B fragments from LDS (swizzled, conflict-free b128) ----
        #pragma unroll
        for (int q = 0; q < 2; ++q) {
            const int n = (wave * 2 + q) * 16 + nl;
            const int slot = (gl + (n >> 1)) & 3;
            bfh[q].v = ((const uint4*)Bh)[n * 4 + slot];
            bfl[q].v = ((const uint4*)Bl)[n * 4 + slot];
        }
        // ---- 18 MFMAs: xh*hh + xl*hh + xh*hl ----
        #pragma unroll
        for (int q = 0; q < 2; ++q)
            #pragma unroll
            for (int mt = 0; mt < 3; ++mt) {
                acc[q][mt] = __builtin_amdgcn_mfma_f32_16x16x32_bf16(
                    afh[mt].s8, bfh[q].s8, acc[q][mt], 0, 0, 0);
                acc[q][mt] = __builtin_amdgcn_mfma_f32_16x16x32_bf16(
                    afh[mt].s8, bfl[q].s8, acc[q][mt], 0, 0, 0);
                acc[q][mt] = __builtin_amdgcn_mfma_f32_16x16x32_bf16(
                    afl[mt].s8, bfh[q].s8, acc[q][mt], 0, 0, 0);
            }
        __syncthreads();
    }

    // ---- epilogue: C/D layout col=lane&15 (=t), row=(lane>>4)*4+r (=band) ----
    #pragma unroll
    for (int q = 0; q < 2; ++q) {
        const int t = t0 + (wave * 2 + q) * 16 + nl;
        #pragma unroll
        for (int mt = 0; mt < 3; ++mt)
            #pragma unroll
            for (int r = 0; r < 4; ++r) {
                const int band = mt * 16 + gl * 4 + r;
                if (band < NBANDS)
                    out[((size_t)b * NBANDS + band) * T_LEN + t] = acc[q][mt][r];
            }
    }
}

extern "C" void kernel_launch(void* const* d_in, const int* in_sizes, int n_in,
                              void* d_out, int out_size, void* d_ws, size_t ws_size,
                              hipStream_t stream) {
    const float* x    = (const float*)d_in[0];
    const float* kern = (const float*)d_in[1];
    float* out        = (float*)d_out;
    ushort* Ah = (ushort*)d_ws;                 // 75*64*8 bf16 = 76.8 KB
    ushort* Al = Ah + 75 * 64 * 8;              // + 76.8 KB  (ws >= 153.6 KB)
    prep_filters<<<75, 64, 0, stream>>>(kern, Ah, Al);
    conv_mfma<<<BATCH * (T_LEN / BN), 256, 0, stream>>>(x, Ah, Al, out);
}

// Round 3
// 298.306 us; speedup vs baseline: 3.2453x; 1.1484x over previous
//
#include <hip/hip_runtime.h>

// CombinedBandPassFilter as MFMA GEMM (bf16 3-term split, fp32 acc):
//   out[b, band, t] = sum_k H[band,k] * x[b, t+k-384]
// Round-3 structure: barrier-free K-loop.
//   - x window converted to bf16 hi/lo ONCE per block into 4 shifted LDS
//     copies (copy_s[i] = w[i+s]); lane reads its B-fragment directly with
//     two aligned ds_read_b64 from copy (n&3) -> conflict-free by layout
//     (copy stride 1952 B = bank offset 8; lane bank = 8*(nl&3)+2*(nl>>2)).
//   - A fragments pre-packed in MFMA lane order in d_ws (prep kernel),
//     loaded global->VGPR per step (153.6 KB total, L2-resident).
//   - No LDS writes / no __syncthreads inside the 25-step K-loop.

typedef __attribute__((ext_vector_type(8))) short short8;
typedef __attribute__((ext_vector_type(4))) float f32x4;

#define T_LEN    32768
#define BATCH    32
#define NBANDS   40
#define KTAPS    769
#define NSTEP    25            // 25*32 = 800 padded taps
#define PADL     384
#define BN       128
#define CP_ELEMS 976           // copy stride in bf16 elems (1952 B -> +8 banks/copy)
#define NCHUNK   464           // 4 copies * 116 chunks of 8 elems (928/copy)

__device__ __forceinline__ ushort f2bf(float f) {          // RNE float->bf16
    unsigned u = __float_as_uint(f);
    return (ushort)((u + 0x7FFFu + ((u >> 16) & 1u)) >> 16);
}
__device__ __forceinline__ float bf2f(ushort h) {
    return __uint_as_float(((unsigned)h) << 16);
}

// Pack H into MFMA A-fragment order: Ah/Al[(c*3+mt)*64 + lane] = 8 bf16
// (band = mt*16 + (lane&15), k = c*32 + 8*(lane>>4) + j), zero-padded.
__global__ void prep_filters(const float* __restrict__ kern,
                             ushort* __restrict__ Ah, ushort* __restrict__ Al) {
    const int blk = blockIdx.x;            // 0..74 = c*3 + mt
    const int c = blk / 3, mt = blk - 3 * c;
    const int l = threadIdx.x;
    const int band = mt * 16 + (l & 15);
    const int kb = c * 32 + 8 * (l >> 4);
    union { ushort u[8]; uint4 v; } ah, al;
    #pragma unroll
    for (int j = 0; j < 8; ++j) {
        const int k = kb + j;
        const float h = (band < NBANDS && k < KTAPS) ? kern[band * KTAPS + k] : 0.f;
        const ushort hh = f2bf(h);
        ah.u[j] = hh;
        al.u[j] = f2bf(h - bf2f(hh));
    }
    ((uint4*)Ah)[blk * 64 + l] = ah.v;
    ((uint4*)Al)[blk * 64 + l] = al.v;
}

__global__ __launch_bounds__(256, 4)
void conv_mfma(const float* __restrict__ x,
               const ushort* __restrict__ Ah, const ushort* __restrict__ Al,
               float* __restrict__ out) {
    __shared__ ushort xsh[4 * CP_ELEMS];   // 4 shifted hi copies
    __shared__ ushort xsl[4 * CP_ELEMS];   // 4 shifted lo copies

    const int tid = threadIdx.x;
    const int bx  = blockIdx.x;
    const int b   = bx >> 8;
    const int tile = bx & 255;
    const int t0  = tile * BN;
    const float* xb = x + (size_t)b * T_LEN;
    const bool interior = (tile >= 3) && (tile <= 251);

    // ---- stage: convert window once into 4 shifted bf16 hi/lo copies ----
    for (int ci = tid; ci < NCHUNK; ci += 256) {
        const int s = ci & 3, m = ci >> 2;         // copy s, 8-elem chunk m
        const int gbase = t0 - PADL + 8 * m + s;   // copy_s[8m..8m+8) = w[8m+s..]
        float v[8];
        if (interior) {
            #pragma unroll
            for (int j = 0; j < 8; ++j) v[j] = xb[gbase + j];
        } else {
            #pragma unroll
            for (int j = 0; j < 8; ++j) {
                const int g = gbase + j;
                v[j] = (g >= 0 && g < T_LEN) ? xb[g] : 0.f;
            }
        }
        union { ushort u[8]; uint4 q; } hi, lo;
        #pragma unroll
        for (int j = 0; j < 8; ++j) {
            const ushort h = f2bf(v[j]);
            hi.u[j] = h;
            lo.u[j] = f2bf(v[j] - bf2f(h));
        }
        *(uint4*)(xsh + s * CP_ELEMS + 8 * m) = hi.q;
        *(uint4*)(xsl + s * CP_ELEMS + 8 * m) = lo.q;
    }
    __syncthreads();

    const int wave = tid >> 6, l = tid & 63;
    const int nl = l & 15, gl = l >> 4;
    const int cs = nl & 3;

    // per-q aligned LDS element offset: copy cs, index (n - cs) + 8*gl
    int off[2];
    #pragma unroll
    for (int q = 0; q < 2; ++q)
        off[q] = cs * CP_ELEMS + (wave * 2 + q) * 16 + (nl - cs) + 8 * gl;

    f32x4 acc[2][3];
    #pragma unroll
    for (int q = 0; q < 2; ++q)
        #pragma unroll
        for (int mt = 0; mt < 3; ++mt)
            acc[q][mt] = (f32x4){0.f, 0.f, 0.f, 0.f};

    const uint4* Ah4 = (const uint4*)Ah + l;
    const uint4* Al4 = (const uint4*)Al + l;

    for (int c = 0; c < NSTEP; ++c) {
        union { uint4 v; short8 s8; } afh[3], afl[3], bfh[2], bfl[2];
        #pragma unroll
        for (int mt = 0; mt < 3; ++mt) {
            afh[mt].v = Ah4[(c * 3 + mt) * 64];
            afl[mt].v = Al4[(c * 3 + mt) * 64];
        }
        #pragma unroll
        for (int q = 0; q < 2; ++q) {
            const ushort* ph = xsh + off[q] + 32 * c;
            const ushort* pl = xsl + off[q] + 32 * c;
            const uint2 h0 = *(const uint2*)ph, h1 = *(const uint2*)(ph + 4);
            const uint2 l0 = *(const uint2*)pl, l1 = *(const uint2*)(pl + 4);
            bfh[q].v = make_uint4(h0.x, h0.y, h1.x, h1.y);
            bfl[q].v = make_uint4(l0.x, l0.y, l1.x, l1.y);
        }
        #pragma unroll
        for (int q = 0; q < 2; ++q)
            #pragma unroll
            for (int mt = 0; mt < 3; ++mt) {
                acc[q][mt] = __builtin_amdgcn_mfma_f32_16x16x32_bf16(
                    afh[mt].s8, bfh[q].s8, acc[q][mt], 0, 0, 0);
                acc[q][mt] = __builtin_amdgcn_mfma_f32_16x16x32_bf16(
                    afh[mt].s8, bfl[q].s8, acc[q][mt], 0, 0, 0);
                acc[q][mt] = __builtin_amdgcn_mfma_f32_16x16x32_bf16(
                    afl[mt].s8, bfh[q].s8, acc[q][mt], 0, 0, 0);
            }
    }

    // ---- epilogue: C/D layout col=lane&15 (=t), row=(lane>>4)*4+r (=band) ----
    #pragma unroll
    for (int q = 0; q < 2; ++q) {
        const int t = t0 + (wave * 2 + q) * 16 + nl;
        #pragma unroll
        for (int mt = 0; mt < 3; ++mt)
            #pragma unroll
            for (int r = 0; r < 4; ++r) {
                const int band = mt * 16 + gl * 4 + r;
                if (band < NBANDS)
                    out[((size_t)b * NBANDS + band) * T_LEN + t] = acc[q][mt][r];
            }
    }
}

extern "C" void kernel_launch(void* const* d_in, const int* in_sizes, int n_in,
                              void* d_out, int out_size, void* d_ws, size_t ws_size,
                              hipStream_t stream) {
    const float* x    = (const float*)d_in[0];
    const float* kern = (const float*)d_in[1];
    float* out        = (float*)d_out;
    ushort* Ah = (ushort*)d_ws;                 // 75*64*8 bf16 = 76.8 KB
    ushort* Al = Ah + 75 * 64 * 8;              // + 76.8 KB (ws >= 153.6 KB)
    prep_filters<<<75, 64, 0, stream>>>(kern, Ah, Al);
    conv_mfma<<<BATCH * (T_LEN / BN), 256, 0, stream>>>(x, Ah, Al, out);
}